// Round 5
// baseline (34.403 us; speedup 1.0000x reference)
//
#include <hip/hip_runtime.h>

#define RR 256
#define LAMBDA_TV 1e-5f
#define TV_EPS 1e-9f

typedef int i32x4 __attribute__((ext_vector_type(4)));

// K1: conditional zero. Read d_out (non-temporal, don't evict density lines
// from L2), write zeros only where bits are nonzero. Correct for ARBITRARY
// prior contents (poison 0xAA.., stale grads, or zeros), so each call is
// deterministic: after K1 the buffer is all-zero regardless of history.
// Steady-state replays: 33.5 MB streaming read + only ~16 MB of writes
// (previously-touched lines) instead of a 33.5 MB write stream.
__global__ void cond_zero_kernel(i32x4* __restrict__ out4, int n4) {
    int tid = blockIdx.x * blockDim.x + threadIdx.x;
    int nthreads = gridDim.x * blockDim.x;
    i32x4 zz = {0, 0, 0, 0};
    for (int k = tid; k < n4; k += nthreads) {
        i32x4 v = __builtin_nontemporal_load(&out4[k]);
        // int compare: treats -0.0f (0x80000000) as nonzero -> overwritten; safe.
        if ((v.x | v.y | v.z | v.w) != 0) {
            out4[k] = zz;
        }
    }
}

// K2: one thread per sparse cell, gather + compute + atomic scatter.
// cell = x*R^2 + y*R + z  =>  links[x,y,z] == links_flat[cell]
// neighbors: +x -> cell + R*R, +y -> cell + R, +z -> cell + 1
__global__ void tv_grad_kernel(const float* __restrict__ density,
                               const int* __restrict__ links,
                               const int* __restrict__ cells,
                               float* __restrict__ grad,
                               int num_cells) {
    int i = blockIdx.x * blockDim.x + threadIdx.x;
    if (i >= num_cells) return;

    int cell = cells[i];
    int z = cell & (RR - 1);
    int y = (cell >> 8) & (RR - 1);
    int x = cell >> 16;

    bool in100 = (x + 1 < RR);
    bool in010 = (y + 1 < RR);
    bool in001 = (z + 1 < RR);

    int l000 = links[cell];
    int l100 = in100 ? links[cell + RR * RR] : -1;
    int l010 = in010 ? links[cell + RR] : -1;
    int l001 = in001 ? links[cell + 1] : -1;

    float v000 = (l000 >= 0) ? density[l000] : 0.0f;
    float v100 = in100 ? ((l100 >= 0) ? density[l100] : 0.0f) : v000;
    float v010 = in010 ? ((l010 >= 0) ? density[l010] : 0.0f) : v000;
    float v001 = in001 ? ((l001 >= 0) ? density[l001] : 0.0f) : v000;

    const float s = RR * 0.5f;
    float dx = (v100 - v000) * s;
    float dy = (v010 - v000) * s;
    float dz = (v001 - v000) * s;

    float idelta = LAMBDA_TV * rsqrtf(TV_EPS + dx * dx + dy * dy + dz * dz);

    if (l000 >= 0) atomicAdd(&grad[l000], -(dx + dy + dz) * idelta);
    if (l100 >= 0) atomicAdd(&grad[l100], dx * idelta);
    if (l010 >= 0) atomicAdd(&grad[l010], dy * idelta);
    if (l001 >= 0) atomicAdd(&grad[l001], dz * idelta);
}

extern "C" void kernel_launch(void* const* d_in, const int* in_sizes, int n_in,
                              void* d_out, int out_size, void* d_ws, size_t ws_size,
                              hipStream_t stream) {
    const float* density = (const float*)d_in[0];   // (N, 1) f32
    const int* links     = (const int*)d_in[1];     // (R, R, R) i32
    const int* cells     = (const int*)d_in[2];     // (sparse_num,) i32
    float* out           = (float*)d_out;           // (N, 1) f32

    int num_cells = in_sizes[2];
    int n4 = out_size / 4;               // 2097152 x 16B = 33.5 MB

    // K1: conditional zero (read-mostly in steady state).
    cond_zero_kernel<<<2048, 256, 0, stream>>>((i32x4*)out, n4);

    // K2: gather + compute + atomic scatter.
    const int threads = 256;
    int blocks = (num_cells + threads - 1) / threads;
    tv_grad_kernel<<<blocks, threads, 0, stream>>>(density, links, cells, out, num_cells);
}